// Round 4
// baseline (79.447 us; speedup 1.0000x reference)
//
#include <hip/hip_runtime.h>
#include <cmath>

#define NCLUST 64
#define TSTEPS 32
#define BATCH  64
#define DIM    4096
#define NTH    256
#define NPT    16          // neurons per thread: d = 4*tid + 1024*q + i
#define REFRAC 2

// Raw barrier: drain LDS ops only (lgkmcnt); global stores keep streaming.
#define BAR() do {                                              \
    __builtin_amdgcn_sched_barrier(0);                          \
    asm volatile("s_waitcnt lgkmcnt(0)" ::: "memory");          \
    __builtin_amdgcn_s_barrier();                               \
    __builtin_amdgcn_sched_barrier(0);                          \
} while (0)

// One block (256 threads, 4 waves) per batch row.
// Thread tid owns neurons d = 4*tid + 1024*q + i (q=0..3, i=0..3), which lie
// in clusters c0+i where c0 = 4*(tid&15) — fixed per thread. Lane l of every
// wave owns output-cluster l for the cascade matvec, with its W row
// (sigmoid(nw[l][c]) * gain[l] / 64) resident in 64 VGPRs. Counts go through
// triple-buffered LDS float atomics; ONE barrier per step: after it, every
// wave redundantly computes the 64-wide cascade from 16 broadcast float4
// reads and keeps its 4 per-thread cascade values in registers.
__global__ __launch_bounds__(NTH)
void alif_fwd(const float* __restrict__ x_in,      // (T,B,D)
              const float* __restrict__ threshold, // (D)
              const float* __restrict__ bm_raw,    // scalar
              const float* __restrict__ bs_raw,    // scalar
              const float* __restrict__ nw,        // (NC,NC)
              const float* __restrict__ gain,      // (NC)
              float* __restrict__ out_s,           // (T,B,D)
              float* __restrict__ out_v)           // (T,B,D)
{
    __shared__ __align__(16) float sCnt[3][NCLUST];  // triple-buffered counts
    __shared__ __align__(16) float sCasc[NCLUST];    // cascade redistribute

    const int tid  = threadIdx.x;
    const int lane = tid & 63;
    const int b    = blockIdx.x;
    const int c0   = 4 * (tid & 15);

    // W row for this lane's output cluster, gain/64 folded in.
    float wReg[NCLUST];
    {
        const float g = gain[lane] * (1.0f / 64.0f);
#pragma unroll
        for (int k = 0; k < 16; k++) {
            float4 w4 = *(const float4*)(nw + lane * NCLUST + 4 * k);
            wReg[4*k+0] = g / (1.0f + expf(-w4.x));
            wReg[4*k+1] = g / (1.0f + expf(-w4.y));
            wReg[4*k+2] = g / (1.0f + expf(-w4.z));
            wReg[4*k+3] = g / (1.0f + expf(-w4.w));
        }
    }
    const float beta_m = 1.0f / (1.0f + expf(-bm_raw[0]));
    const float beta_s = 1.0f / (1.0f + expf(-bs_raw[0]));
    const float ombm   = 1.0f - beta_m;
    const float vreset = -0.1f;

    float v_[NPT], is_[NPT], th_[NPT], xA[NPT], xB[NPT];
    int   r_[NPT];
#pragma unroll
    for (int q = 0; q < 4; q++) {
        float4 t4 = *(const float4*)(threshold + 4 * tid + 1024 * q);
        th_[4*q+0] = t4.x; th_[4*q+1] = t4.y; th_[4*q+2] = t4.z; th_[4*q+3] = t4.w;
    }
#pragma unroll
    for (int i = 0; i < NPT; i++) { v_[i] = 0.f; is_[i] = 0.f; r_[i] = 0; }

    if (tid < NCLUST) { sCnt[0][tid] = 0.f; sCnt[1][tid] = 0.f; sCnt[2][tid] = 0.f; }

    const size_t strideT = (size_t)BATCH * DIM;
    const float* xb = x_in + (size_t)b * DIM + 4 * tid;
    float* sp = out_s + (size_t)b * DIM + 4 * tid;
    float* vp = out_v + (size_t)b * DIM + 4 * tid;

    // depth-2 prefetch
#pragma unroll
    for (int q = 0; q < 4; q++) {
        float4 a4 = *(const float4*)(xb + 1024 * q);
        xA[4*q+0] = a4.x; xA[4*q+1] = a4.y; xA[4*q+2] = a4.z; xA[4*q+3] = a4.w;
        float4 b4 = *(const float4*)(xb + strideT + 1024 * q);
        xB[4*q+0] = b4.x; xB[4*q+1] = b4.y; xB[4*q+2] = b4.z; xB[4*q+3] = b4.w;
    }

    float cpA0 = 0.f, cpA1 = 0.f, cpA2 = 0.f, cpA3 = 0.f;  // cascade (prev step)
    int slot = 0;

    __syncthreads();   // one-time init barrier

#define STEP(T_, XC)                                                          \
    {                                                                         \
        float cadd0 = 0.f, cadd1 = 0.f, cadd2 = 0.f, cadd3 = 0.f;             \
        float* stp = sp + (size_t)(T_) * strideT;                             \
        float* vtp = vp + (size_t)(T_) * strideT;                             \
        _Pragma("unroll")                                                     \
        for (int q = 0; q < 4; q++) {                                         \
            float s4[4], v4o[4];                                              \
            _Pragma("unroll")                                                 \
            for (int i = 0; i < 4; i++) {                                     \
                const int n = 4 * q + i;                                      \
                const float cpi = (i == 0) ? cpA0 : (i == 1) ? cpA1           \
                                 : (i == 2) ? cpA2 : cpA3;                    \
                float is = beta_s * (is_[n] + cpi) + XC[n];                   \
                float vn = beta_m * v_[n] + ombm * is;                        \
                float vv = (r_[n] > 0) ? vreset : vn;                         \
                bool  spk = (vv >= th_[n]);                                   \
                float sv = spk ? 1.0f : 0.0f;                                 \
                v_[n]  = spk ? (vv - th_[n]) : vv;                            \
                r_[n]  = spk ? REFRAC : ((r_[n] > 0) ? r_[n] - 1 : 0);        \
                is_[n] = is;                                                  \
                s4[i] = sv; v4o[i] = v_[n];                                   \
                if (i == 0) cadd0 += sv; else if (i == 1) cadd1 += sv;        \
                else if (i == 2) cadd2 += sv; else cadd3 += sv;               \
            }                                                                 \
            *(float4*)(stp + 1024 * q) = make_float4(s4[0], s4[1], s4[2], s4[3]); \
            *(float4*)(vtp + 1024 * q) = make_float4(v4o[0], v4o[1], v4o[2], v4o[3]); \
        }                                                                     \
        atomicAdd(&sCnt[slot][c0 + 0], cadd0);                                \
        atomicAdd(&sCnt[slot][c0 + 1], cadd1);                                \
        atomicAdd(&sCnt[slot][c0 + 2], cadd2);                                \
        atomicAdd(&sCnt[slot][c0 + 3], cadd3);                                \
        const int nslot = (slot == 2) ? 0 : slot + 1;                         \
        sCnt[nslot][lane] = 0.f;   /* reset slot for step T_+1 (see proof) */ \
        if ((T_) + 2 < TSTEPS) {                                              \
            const float* xf = xb + (size_t)((T_) + 2) * strideT;              \
            _Pragma("unroll")                                                 \
            for (int q = 0; q < 4; q++) {                                     \
                float4 f4 = *(const float4*)(xf + 1024 * q);                  \
                XC[4*q+0] = f4.x; XC[4*q+1] = f4.y;                           \
                XC[4*q+2] = f4.z; XC[4*q+3] = f4.w;                           \
            }                                                                 \
        }                                                                     \
        BAR();                                                                \
        {                                                                     \
            float a0 = 0.f, a1 = 0.f, a2 = 0.f, a3 = 0.f;                     \
            _Pragma("unroll")                                                 \
            for (int k = 0; k < 16; k++) {                                    \
                float4 c4 = *(const float4*)&sCnt[slot][4 * k];               \
                a0 += c4.x * wReg[4*k+0];                                     \
                a1 += c4.y * wReg[4*k+1];                                     \
                a2 += c4.z * wReg[4*k+2];                                     \
                a3 += c4.w * wReg[4*k+3];                                     \
            }                                                                 \
            sCasc[lane] = (a0 + a1) + (a2 + a3);  /* all waves: same values */ \
            float4 cv = *(const float4*)&sCasc[c0];                           \
            cpA0 = cv.x; cpA1 = cv.y; cpA2 = cv.z; cpA3 = cv.w;               \
            slot = nslot;                                                     \
        }                                                                     \
    }

    for (int t = 0; t < TSTEPS; t += 2) {
        STEP(t,     xA)
        STEP(t + 1, xB)
    }
#undef STEP
}

extern "C" void kernel_launch(void* const* d_in, const int* in_sizes, int n_in,
                              void* d_out, int out_size, void* d_ws, size_t ws_size,
                              hipStream_t stream) {
    const float* x  = (const float*)d_in[0];
    const float* th = (const float*)d_in[1];
    const float* bm = (const float*)d_in[2];
    const float* bs = (const float*)d_in[3];
    const float* nw = (const float*)d_in[4];
    const float* gn = (const float*)d_in[5];
    float* out_s = (float*)d_out;
    float* out_v = out_s + (size_t)TSTEPS * BATCH * DIM;

    hipLaunchKernelGGL(alif_fwd, dim3(BATCH), dim3(NTH), 0, stream,
                       x, th, bm, bs, nw, gn, out_s, out_v);
}

// Round 5
// 71.337 us; speedup vs baseline: 1.1137x; 1.1137x over previous
//
#include <hip/hip_runtime.h>
#include <cmath>

#define NCLUST 64
#define TSTEPS 32
#define BATCH  64
#define DIM    4096
#define NTH    1024
#define PARTS  4                 // blocks per batch row
#define DPART  (DIM / PARTS)     // 1024 neurons per block (1 per thread)
#define REFRAC 2

// Raw barrier: drain LDS ops only; global stores/loads keep streaming.
#define BAR() do {                                              \
    __builtin_amdgcn_sched_barrier(0);                          \
    asm volatile("s_waitcnt lgkmcnt(0)" ::: "memory");          \
    __builtin_amdgcn_s_barrier();                               \
    __builtin_amdgcn_sched_barrier(0);                          \
} while (0)

// Grid: 256 blocks = (row b = blockIdx>>2, part = blockIdx&3). Thread owns
// neuron d = part*1024 + tid; cluster(d) = d%64 = tid&63 = lane. Per step:
// phase1 (decay+spike+stores, LDS count atomics) -> BAR -> wave 0 publishes
// block counts to gCnt[t][b][lane] via device-scope atomicAdd of
// (cnt | 1<<20), spins until arrival field == PARTS (the count word IS the
// flag), does the 64x64 matvec with W*gain/64 held in 64 VGPRs -> BAR ->
// everyone reads the cascade. gCnt has one slot per step (memset per launch),
// so there are no resets, no fences, and no cross-replay state.
__global__ __launch_bounds__(NTH)
void alif_fwd(const float* __restrict__ x_in,      // (T,B,D)
              const float* __restrict__ threshold, // (D)
              const float* __restrict__ bm_raw,    // scalar
              const float* __restrict__ bs_raw,    // scalar
              const float* __restrict__ nw,        // (NC,NC)
              const float* __restrict__ gain,      // (NC)
              float* __restrict__ out_s,           // (T,B,D)
              float* __restrict__ out_v,           // (T,B,D)
              unsigned int* __restrict__ gCnt)     // (T,B,NC) workspace, zeroed
{
    __shared__ unsigned int sCnt[2][NCLUST];          // double-buffered counts
    __shared__ __align__(16) float sCntF[NCLUST];     // row counts as float
    __shared__ __align__(16) float sCasc[NCLUST];     // cascade broadcast

    const int tid  = threadIdx.x;
    const int lane = tid & 63;
    const int wav  = tid >> 6;
    const int b    = blockIdx.x >> 2;
    const int part = blockIdx.x & 3;

    // Per-lane W row for the matvec (wave 0 uses it): sigmoid(nw[lane][c]) * gain[lane]/64
    float wReg[NCLUST];
    {
        const float g = gain[lane] * (1.0f / 64.0f);
#pragma unroll
        for (int k = 0; k < 16; k++) {
            float4 w4 = *(const float4*)(nw + lane * NCLUST + 4 * k);
            wReg[4*k+0] = g / (1.0f + expf(-w4.x));
            wReg[4*k+1] = g / (1.0f + expf(-w4.y));
            wReg[4*k+2] = g / (1.0f + expf(-w4.z));
            wReg[4*k+3] = g / (1.0f + expf(-w4.w));
        }
    }
    const float beta_m = 1.0f / (1.0f + expf(-bm_raw[0]));
    const float beta_s = 1.0f / (1.0f + expf(-bs_raw[0]));
    const float ombm   = 1.0f - beta_m;
    const float vreset = -0.1f;

    const int d0 = part * DPART + tid;
    const float th = threshold[d0];
    float v = 0.f, is = 0.f;
    int   r = 0;

    const size_t strideT = (size_t)BATCH * DIM;
    const float* xp = x_in  + (size_t)b * DIM + d0;
    float*       sp = out_s + (size_t)b * DIM + d0;
    float*       vp = out_v + (size_t)b * DIM + d0;

    // depth-2 input prefetch
    float xA = xp[0];
    float xB = xp[strideT];

    if (tid < 2 * NCLUST) ((unsigned int*)sCnt)[tid] = 0u;
    __syncthreads();

    float casc = 0.f;

#define STEP(T_, XC, SL)                                                      \
    {                                                                         \
        float isv = beta_s * (is + casc) + XC;                                \
        float vn  = beta_m * v + ombm * isv;                                  \
        float vv  = (r > 0) ? vreset : vn;                                    \
        bool  spk = (vv >= th);                                               \
        float sv  = spk ? 1.0f : 0.0f;                                        \
        v  = spk ? (vv - th) : vv;                                            \
        r  = spk ? REFRAC : ((r > 0) ? r - 1 : 0);                            \
        is = isv;                                                             \
        if (spk) atomicAdd(&sCnt[SL][lane], 1u);                              \
        sp[(size_t)(T_) * strideT] = sv;                                      \
        vp[(size_t)(T_) * strideT] = v;                                       \
        if ((T_) + 2 < TSTEPS) XC = xp[(size_t)((T_) + 2) * strideT];         \
        BAR();                                                                \
        if (wav == 0) {                                                       \
            unsigned int cnt = sCnt[SL][lane];                                \
            sCnt[SL][lane] = 0u;            /* reuse at step T_+2 */          \
            unsigned int* g = gCnt + ((size_t)(T_) * BATCH + b) * NCLUST + lane; \
            atomicAdd(g, cnt + (1u << 20));                                   \
            unsigned int gv;                                                  \
            do {                                                              \
                gv = __hip_atomic_load(g, __ATOMIC_RELAXED,                   \
                                       __HIP_MEMORY_SCOPE_AGENT);             \
            } while (!__all((gv >> 20) == PARTS));                            \
            sCntF[lane] = (float)(gv & 0xFFFFFu);                             \
            float a0 = 0.f, a1 = 0.f, a2 = 0.f, a3 = 0.f;                     \
            _Pragma("unroll")                                                 \
            for (int k = 0; k < 16; k++) {                                    \
                float4 c4 = *(const float4*)&sCntF[4 * k];                    \
                a0 += c4.x * wReg[4*k+0];                                     \
                a1 += c4.y * wReg[4*k+1];                                     \
                a2 += c4.z * wReg[4*k+2];                                     \
                a3 += c4.w * wReg[4*k+3];                                     \
            }                                                                 \
            sCasc[lane] = (a0 + a1) + (a2 + a3);                              \
        }                                                                     \
        BAR();                                                                \
        casc = sCasc[lane];                                                   \
    }

    for (int t = 0; t < TSTEPS; t += 2) {
        STEP(t,     xA, 0)
        STEP(t + 1, xB, 1)
    }
#undef STEP
}

extern "C" void kernel_launch(void* const* d_in, const int* in_sizes, int n_in,
                              void* d_out, int out_size, void* d_ws, size_t ws_size,
                              hipStream_t stream) {
    const float* x  = (const float*)d_in[0];
    const float* th = (const float*)d_in[1];
    const float* bm = (const float*)d_in[2];
    const float* bs = (const float*)d_in[3];
    const float* nw = (const float*)d_in[4];
    const float* gn = (const float*)d_in[5];
    float* out_s = (float*)d_out;
    float* out_v = out_s + (size_t)TSTEPS * BATCH * DIM;

    // One count slot per step: zero once per launch (deterministic; no
    // cross-replay state). 32*64*64*4 = 512 KB.
    hipMemsetAsync(d_ws, 0, (size_t)TSTEPS * BATCH * NCLUST * sizeof(unsigned int), stream);

    hipLaunchKernelGGL(alif_fwd, dim3(BATCH * PARTS), dim3(NTH), 0, stream,
                       x, th, bm, bs, nw, gn, out_s, out_v,
                       (unsigned int*)d_ws);
}